// Round 5
// baseline (50.529 us; speedup 1.0000x reference)
//
#include <hip/hip_runtime.h>
#include <hip/hip_bf16.h>
#include <cstdint>

#define BM 32
#define NTHREADS 640              // 10 waves
#define WS_TILE 524288            // 64 u-steps * 8192 B per weight tensor (bf16 64x64)
#define SMEM_BYTES (4*64*32*4 + 6*32*64*4)   // xS 32768 + pscr 49152 = 81920

typedef __bf16 bf16x8_t __attribute__((ext_vector_type(8)));
typedef float f32x4_t __attribute__((ext_vector_type(4)));

// Prep: fold scales, combine w011 + w101^T(u,v), store FRAGMENT-MAJOR per u-step:
//   ws[tile] + u*8192 + f*1024 + lane*16,  f = n*2+kf
// element (lane, j): w = 16n + (lane&15), v = 8*(lane>>4) + 32*kf + j
__global__ __launch_bounds__(256) void prep_weights(const float* __restrict__ w000,
                                                    const float* __restrict__ w110,
                                                    const float* __restrict__ w011,
                                                    const float* __restrict__ w101,
                                                    char* __restrict__ ws) {
  const float A0  = 0.011048543456039806f;   // sqrt(1/8192) ; also == ALPHA1/sqrt(3)
  const float A0I = A0 * 0.57735026918962576f;
  int t = blockIdx.x * 256 + threadIdx.x;    // 32768 threads: (u, f, lane)
  int u = t >> 9, f = (t >> 6) & 7, l = t & 63;
  int n = f >> 1, kf = f & 1;
  int w = 16 * n + (l & 15);
  int vbase = 8 * (l >> 4) + 32 * kf;
  bf16x8_t p0, p1, pc;
#pragma unroll
  for (int j = 0; j < 8; ++j) {
    int v = vbase + j;
    float a = w000[u * 4096 + v * 64 + w] * A0;
    float b = w110[u * 4096 + v * 64 + w] * A0I;
    float d = (w011[u * 4096 + v * 64 + w] + w101[v * 4096 + u * 64 + w]) * A0;
    p0[j] = (__bf16)a;
    p1[j] = (__bf16)b;
    pc[j] = (__bf16)d;
  }
  int off = u * 8192 + f * 1024 + l * 16;
  *(bf16x8_t*)(ws + off) = p0;
  *(bf16x8_t*)(ws + WS_TILE + off) = p1;
  *(bf16x8_t*)(ws + 2 * WS_TILE + off) = pc;
}

// Main: 256 blocks x 640 threads (10 waves), BM=32 rows/block, 1 block/CU.
// wave = 2*unit + kf.  unit 0: p000 ; unit 1: p110 (dot3 A) ; units 2-4: out1 k=unit-2.
// Each wave handles ONE K-half (kf): 4 B-frags/step streamed GLOBAL->VGPR
// (L2/L1-resident weights), triple-buffered, ZERO barriers in the u-loop.
// kf-pairs sum their accumulators in the epilogue via LDS (disjoint region).
__global__ __launch_bounds__(NTHREADS, 1) void tp_main(const float* __restrict__ x,
                                                       const char* __restrict__ ws,
                                                       float* __restrict__ out) {
  extern __shared__ char smem[];
  float* xS   = (float*)smem;                 // [vec][u][b] f32, 4*64*32 = 32KB
  float* pscr = (float*)(smem + 32768);       // [6][32][64] f32 = 48KB (epilogue only)
  const int tid = threadIdx.x;
  const int wave = tid >> 6, lane = tid & 63;
  const int lr = lane & 15, lg = lane >> 4;
  const int b0 = blockIdx.x * BM;
  const int unit = wave >> 1;                 // 0..4
  const int kf = wave & 1;
  const int tsel = (unit == 0) ? 0 : ((unit == 1) ? 1 : 2);
  const char* gw = ws + tsel * WS_TILE + kf * 1024 + lane * 16;  // + u*8192 + n*2048

  // scalar table xS[vec][u][b]: vec0 = x0, vec 1+i = x1[:,:,i]
  for (int idx = tid; idx < 4 * 64 * 32; idx += NTHREADS) {
    int vec = idx >> 11, rem = idx & 2047;
    int uu = rem >> 5, bb = rem & 31;
    int col = (vec == 0) ? uu : (64 + 3 * uu + (vec - 1));
    xS[idx] = x[(b0 + bb) * 256 + col];
  }

  // per-wave x row-vectors (only this wave's kf half): v = 8*lg + 32*kf + j
  float xp[3][2][8];    // [vi][m][j]; units != 1 use vi=0 only
  if (unit == 1) {
#pragma unroll
    for (int vi = 0; vi < 3; ++vi)
#pragma unroll
      for (int m = 0; m < 2; ++m)
#pragma unroll
        for (int j = 0; j < 8; ++j) {
          int v = 8 * lg + 32 * kf + j;
          xp[vi][m][j] = x[(b0 + 16 * m + lr) * 256 + 64 + 3 * v + vi];
        }
  } else {
#pragma unroll
    for (int m = 0; m < 2; ++m)
#pragma unroll
      for (int j = 0; j < 8; ++j) {
        int v = 8 * lg + 32 * kf + j;
        int col = (unit == 0) ? v : (64 + 3 * v + (unit - 2));
        xp[0][m][j] = x[(b0 + 16 * m + lr) * 256 + col];
      }
  }

  f32x4_t acc[2][4];
#pragma unroll
  for (int m = 0; m < 2; ++m)
#pragma unroll
    for (int n = 0; n < 4; ++n) {
      f32x4_t z = {0.f, 0.f, 0.f, 0.f};
      acc[m][n] = z;
    }

  auto LOADG = [&](bf16x8_t (&bfr)[4], int uu) {
    const char* p = gw + uu * 8192;
#pragma unroll
    for (int n = 0; n < 4; ++n)
      bfr[n] = *(const bf16x8_t*)(p + n * 2048);
  };

  auto STEP = [&](bf16x8_t (&bfr)[4], int uu) {
    bf16x8_t afr[2];
    if (unit == 1) {
#pragma unroll
      for (int m = 0; m < 2; ++m) {
        float s0 = xS[1 * 2048 + uu * 32 + 16 * m + lr];
        float s1 = xS[2 * 2048 + uu * 32 + 16 * m + lr];
        float s2 = xS[3 * 2048 + uu * 32 + 16 * m + lr];
#pragma unroll
        for (int j = 0; j < 8; ++j)
          afr[m][j] = (__bf16)(s0 * xp[0][m][j] + s1 * xp[1][m][j] + s2 * xp[2][m][j]);
      }
    } else {
#pragma unroll
      for (int m = 0; m < 2; ++m) {
        float s = xS[uu * 32 + 16 * m + lr];
#pragma unroll
        for (int j = 0; j < 8; ++j)
          afr[m][j] = (__bf16)(s * xp[0][m][j]);
      }
    }
#pragma unroll
    for (int m = 0; m < 2; ++m)
#pragma unroll
      for (int n = 0; n < 4; ++n)
        acc[m][n] = __builtin_amdgcn_mfma_f32_16x16x32_bf16(afr[m], bfr[n], acc[m][n], 0, 0, 0);
  };

  __syncthreads();   // xS visible; ONLY barrier before epilogue

  // triple-buffered register pipeline, hand-rotated (all indices static)
  bf16x8_t B0[4], B1[4], B2[4];
  LOADG(B0, 0);
  LOADG(B1, 1);
  for (int u = 0; u < 60; u += 3) {
    LOADG(B2, u + 2);
    STEP(B0, u);
    LOADG(B0, u + 3);
    STEP(B1, u + 1);
    LOADG(B1, u + 4);
    STEP(B2, u + 2);
  }
  LOADG(B2, 62);
  STEP(B0, 60);
  LOADG(B0, 63);
  STEP(B1, 61);
  STEP(B2, 62);
  STEP(B0, 63);

  // ---- epilogue (pscr disjoint from xS: no alias with free-running waves) ----
  // phase 1: kf=1 waves dump acc
  if (kf == 1) {
#pragma unroll
    for (int m = 0; m < 2; ++m)
#pragma unroll
      for (int n = 0; n < 4; ++n)
#pragma unroll
        for (int r = 0; r < 4; ++r)
          pscr[unit * 2048 + (16 * m + 4 * lg + r) * 64 + 16 * n + lr] = acc[m][n][r];
  }
  __syncthreads();
  // phase 2: kf=0 waves fold in their pair's half; unit 1 republishes p110 sum
  if (kf == 0) {
#pragma unroll
    for (int m = 0; m < 2; ++m)
#pragma unroll
      for (int n = 0; n < 4; ++n)
#pragma unroll
        for (int r = 0; r < 4; ++r)
          acc[m][n][r] += pscr[unit * 2048 + (16 * m + 4 * lg + r) * 64 + 16 * n + lr];
    if (unit == 1) {
#pragma unroll
      for (int m = 0; m < 2; ++m)
#pragma unroll
        for (int n = 0; n < 4; ++n)
#pragma unroll
          for (int r = 0; r < 4; ++r)
            pscr[5 * 2048 + (16 * m + 4 * lg + r) * 64 + 16 * n + lr] = acc[m][n][r];
    }
  }
  __syncthreads();
  // phase 3: stores
  if (wave == 0) {                  // out0 = p000 + p110
#pragma unroll
    for (int m = 0; m < 2; ++m)
#pragma unroll
      for (int n = 0; n < 4; ++n)
#pragma unroll
        for (int r = 0; r < 4; ++r) {
          int row = 16 * m + 4 * lg + r, col = 16 * n + lr;
          out[(b0 + row) * 256 + col] = acc[m][n][r] + pscr[5 * 2048 + row * 64 + col];
        }
  } else if (kf == 0 && unit >= 2) {  // out1, k = unit-2
    const int k = unit - 2;
#pragma unroll
    for (int m = 0; m < 2; ++m)
#pragma unroll
      for (int n = 0; n < 4; ++n)
#pragma unroll
        for (int r = 0; r < 4; ++r) {
          int row = 16 * m + 4 * lg + r, col = 16 * n + lr;
          out[(b0 + row) * 256 + 64 + 3 * col + k] = acc[m][n][r];
        }
  }
}

extern "C" void kernel_launch(void* const* d_in, const int* in_sizes, int n_in,
                              void* d_out, int out_size, void* d_ws, size_t ws_size,
                              hipStream_t stream) {
  const float* x    = (const float*)d_in[0];
  const float* w000 = (const float*)d_in[1];
  const float* w110 = (const float*)d_in[2];
  const float* w011 = (const float*)d_in[3];
  const float* w101 = (const float*)d_in[4];
  float* out = (float*)d_out;
  char* ws = (char*)d_ws;

  prep_weights<<<128, 256, 0, stream>>>(w000, w110, w011, w101, ws);

  hipFuncSetAttribute((const void*)tp_main, hipFuncAttributeMaxDynamicSharedMemorySize, SMEM_BYTES);
  tp_main<<<256, NTHREADS, SMEM_BYTES, stream>>>(x, ws, out);
}